// Round 1
// 610.601 us; speedup vs baseline: 1.2050x; 1.2050x over previous
//
#include <hip/hip_runtime.h>
#include <cstddef>

// Shapes (fixed): B=1, S=256, H=8, D=64
//   c,b,a: [256, 8, 64]   (r/q/p, n, k/j/i)  row-major
//   W:     [8, 64, 64, 64] (n, i, j, k)      row-major
//   out:   [8, 256, 256, 256] (n, p, q, r)   row-major, fp32, 512 MiB
//
// Pipeline (ws scratch):
//   bs[q,j]         = sum_n b[q,n,j]                         fp32, 64 KiB
//   Ah/Al[n*256+p][i] = bf16 hi/lo split of a[p,n,i]         (row-swizzled)
//   T1[(i*256+r),j] = sum_{n,k} c[r,n,k] * W[n,i,j,k]        fp32, 4 MiB
//   T2t_h/l[q][r][i]= bf16 hi/lo of sum_j bs[q,j]*T1[(i,r),j] (row-swizzled, 8 MiB each)
//   out[n,p,q,r]    = sum_i a[p,n,i] * T2[q,i,r]
//                   = MFMA GEMM: C[2048 x 65536] = Ah*Bh + Ah*Bl + Al*Bh, K=64
//
// Swizzle convention (shared by producers and step3's ds_read):
//   within each 128-byte row (64 bf16), byte_off ^= ((row & 7) << 4)
//   -> linear global_load_lds staging + swizzled ds_read_b128 = conflict-free (2-way).

#define LDS_STRIDE 68  // fp32 tile kernels: 16B-aligned rows, <=2-way bank aliasing

typedef __attribute__((ext_vector_type(8))) short bf16x8;
typedef __attribute__((ext_vector_type(4))) float f32x4;

__device__ __forceinline__ unsigned short f32_to_bf16_rn(float x) {
    unsigned u = __float_as_uint(x);
    u += 0x7fffu + ((u >> 16) & 1u);  // round-to-nearest-even; inputs finite
    return (unsigned short)(u >> 16);
}
__device__ __forceinline__ float bf16_to_f32(unsigned short h) {
    return __uint_as_float(((unsigned)h) << 16);
}
__device__ __forceinline__ void gld_lds16(const void* g, void* l) {
    __builtin_amdgcn_global_load_lds(
        (const __attribute__((address_space(1))) unsigned*)g,
        (__attribute__((address_space(3))) unsigned*)l, 16, 0, 0);
}

__global__ __launch_bounds__(256) void bsum_kernel(const float* __restrict__ b,
                                                   float* __restrict__ bs) {
    int t = blockIdx.x * 256 + threadIdx.x;  // 0..16383
    int q = t >> 6, j = t & 63;
    float s = 0.f;
#pragma unroll
    for (int n = 0; n < 8; ++n) s += b[q * 512 + n * 64 + j];
    bs[t] = s;
}

// a[p][n][i] -> Ah/Al[row=n*256+p][i] bf16 hi/lo, in-row XOR swizzle.
__global__ __launch_bounds__(256) void aprep_kernel(const float* __restrict__ a,
                                                    unsigned short* __restrict__ Ah,
                                                    unsigned short* __restrict__ Al) {
    const int g = blockIdx.x * 256 + threadIdx.x;  // 32768 threads, 4 i each
    const int row = g >> 4;                        // 0..2047 = n*256+p
    const int i0 = (g & 15) * 4;
    const int p = row & 255, n = row >> 8;
    const float4 v = *(const float4*)&a[p * 512 + n * 64 + i0];
    const float xs[4] = {v.x, v.y, v.z, v.w};
    unsigned short h[4], l[4];
#pragma unroll
    for (int e = 0; e < 4; ++e) {
        h[e] = f32_to_bf16_rn(xs[e]);
        l[e] = f32_to_bf16_rn(xs[e] - bf16_to_f32(h[e]));
    }
    uint2 vh, vl;
    vh.x = (unsigned)h[0] | ((unsigned)h[1] << 16);
    vh.y = (unsigned)h[2] | ((unsigned)h[3] << 16);
    vl.x = (unsigned)l[0] | ((unsigned)l[1] << 16);
    vl.y = (unsigned)l[2] | ((unsigned)l[3] << 16);
    const int boff = (i0 * 2) ^ ((row & 7) << 4);  // stays 8B-aligned (XOR hits bits 4..6)
    *(uint2*)((char*)Ah + (size_t)row * 128 + boff) = vh;
    *(uint2*)((char*)Al + (size_t)row * 128 + boff) = vl;
}

// T1[(i*256+r)*64 + j] = sum_{nk} c[r*512 + nk] * W[n*262144 + i*4096 + j*64 + k]
// GEMM per i: M=256(r) x N=64(j) x K=512(nk). Block = one (i, r-tile-of-64).
__global__ __launch_bounds__(256) void step1_kernel(const float* __restrict__ c,
                                                    const float* __restrict__ W,
                                                    float* __restrict__ T1) {
    __shared__ alignas(16) float As[16 * LDS_STRIDE];
    __shared__ alignas(16) float Bs[16 * LDS_STRIDE];
    const int i  = blockIdx.x;       // 0..63
    const int r0 = blockIdx.y * 64;  // 0..3 * 64
    const int t  = threadIdx.x;
    const int tx = t & 15, ty = t >> 4;
    float acc[4][4] = {};

    for (int kk0 = 0; kk0 < 512; kk0 += 16) {
        {
            const int kc = t & 15, rb = t >> 4;
#pragma unroll
            for (int ii = 0; ii < 4; ++ii) {
                const int row = rb + ii * 16;
                As[kc * LDS_STRIDE + row] = c[(r0 + row) * 512 + kk0 + kc];
            }
        }
        {
            const int nw = kk0 >> 6, k0 = kk0 & 63;
            const float* wbase = W + nw * 262144 + i * 4096 + k0;
            const int kc = t & 15, jb = t >> 4;
#pragma unroll
            for (int ii = 0; ii < 4; ++ii) {
                const int j = jb + ii * 16;
                Bs[kc * LDS_STRIDE + j] = wbase[j * 64 + kc];
            }
        }
        __syncthreads();
#pragma unroll
        for (int k = 0; k < 16; ++k) {
            const float4 av = *(const float4*)&As[k * LDS_STRIDE + ty * 4];
            const float4 bv = *(const float4*)&Bs[k * LDS_STRIDE + tx * 4];
            const float aa[4] = {av.x, av.y, av.z, av.w};
            const float bb[4] = {bv.x, bv.y, bv.z, bv.w};
#pragma unroll
            for (int u = 0; u < 4; ++u)
#pragma unroll
                for (int v = 0; v < 4; ++v) acc[u][v] += aa[u] * bb[v];
        }
        __syncthreads();
    }
#pragma unroll
    for (int u = 0; u < 4; ++u) {
        const int r = r0 + ty * 4 + u;
        float4 v4 = make_float4(acc[u][0], acc[u][1], acc[u][2], acc[u][3]);
        *(float4*)&T1[(i * 256 + r) * 64 + tx * 4] = v4;
    }
}

// T2t[q][r][i] = sum_j bs[q*64+j] * T1[(i*256+r)*64 + j]
// NT GEMM per r: M=64(q-tile) x N=64(i) x K=64(j). Output: bf16 hi/lo, row-swizzled.
__global__ __launch_bounds__(256) void step2_kernel(const float* __restrict__ bs,
                                                    const float* __restrict__ T1,
                                                    unsigned short* __restrict__ T2h,
                                                    unsigned short* __restrict__ T2l) {
    __shared__ alignas(16) float As[16 * LDS_STRIDE];
    __shared__ alignas(16) float Bs[16 * LDS_STRIDE];
    const int r  = blockIdx.x;       // 0..255
    const int q0 = blockIdx.y * 64;  // 0..3 * 64
    const int t  = threadIdx.x;
    const int tx = t & 15, ty = t >> 4;
    float acc[4][4] = {};

    for (int kk0 = 0; kk0 < 64; kk0 += 16) {
        const int kc = t & 15, rb = t >> 4;
#pragma unroll
        for (int ii = 0; ii < 4; ++ii) {
            const int row = rb + ii * 16;
            As[kc * LDS_STRIDE + row] = bs[(q0 + row) * 64 + kk0 + kc];
        }
#pragma unroll
        for (int ii = 0; ii < 4; ++ii) {
            const int irow = rb + ii * 16;  // i index 0..63
            Bs[kc * LDS_STRIDE + irow] = T1[(irow * 256 + r) * 64 + kk0 + kc];
        }
        __syncthreads();
#pragma unroll
        for (int k = 0; k < 16; ++k) {
            const float4 av = *(const float4*)&As[k * LDS_STRIDE + ty * 4];
            const float4 bv = *(const float4*)&Bs[k * LDS_STRIDE + tx * 4];
            const float aa[4] = {av.x, av.y, av.z, av.w};
            const float bb[4] = {bv.x, bv.y, bv.z, bv.w};
#pragma unroll
            for (int u = 0; u < 4; ++u)
#pragma unroll
                for (int v = 0; v < 4; ++v) acc[u][v] += aa[u] * bb[v];
        }
        __syncthreads();
    }
    // epilogue: thread holds T2t[q0+ty*4+u][r][tx*4+v]; write bf16 hi/lo swizzled
    const int boff = (tx * 8) ^ ((r & 7) << 4);
    char* baseH = (char*)T2h + (size_t)r * 128 + boff;
    char* baseL = (char*)T2l + (size_t)r * 128 + boff;
#pragma unroll
    for (int u = 0; u < 4; ++u) {
        const int q = q0 + ty * 4 + u;
        unsigned short h[4], l[4];
#pragma unroll
        for (int v = 0; v < 4; ++v) {
            const float x = acc[u][v];
            h[v] = f32_to_bf16_rn(x);
            l[v] = f32_to_bf16_rn(x - bf16_to_f32(h[v]));
        }
        uint2 vh, vl;
        vh.x = (unsigned)h[0] | ((unsigned)h[1] << 16);
        vh.y = (unsigned)h[2] | ((unsigned)h[3] << 16);
        vl.x = (unsigned)l[0] | ((unsigned)l[1] << 16);
        vl.y = (unsigned)l[2] | ((unsigned)l[3] << 16);
        *(uint2*)(baseH + (size_t)q * 32768) = vh;
        *(uint2*)(baseL + (size_t)q * 32768) = vl;
    }
}

// out viewed as C[2048][65536], row=n*256+p, col=q*256+r.
// C = Ah*Bh + Ah*Bl + Al*Bh   (split-bf16, fp32 MFMA accumulate), K=64(i).
// Block: 128 rows x 128 cols, 4 waves (each 64x64 = 4x4 MFMA 16x16 fragments).
__global__ __launch_bounds__(256) void step3_kernel(const unsigned short* __restrict__ Ah,
                                                    const unsigned short* __restrict__ Al,
                                                    const unsigned short* __restrict__ T2h,
                                                    const unsigned short* __restrict__ T2l,
                                                    float* __restrict__ out) {
    __shared__ alignas(16) unsigned short sAh[8192];  // [128 rows][64 i] bf16, swizzled
    __shared__ alignas(16) unsigned short sAl[8192];
    __shared__ alignas(16) unsigned short sBh[8192];  // [128 r][64 i]
    __shared__ alignas(16) unsigned short sBl[8192];
    const int q  = blockIdx.y;       // 0..255
    const int rt = blockIdx.x >> 1;  // row tile 0..15 (128 rows each)
    const int rh = blockIdx.x & 1;   // r half 0..1   (128 r each)
    const int t  = threadIdx.x;

    // stage: 4 buffers x 16KB, linear (global already carries the row swizzle)
    const char* gAh = (const char*)Ah + (size_t)rt * 16384;
    const char* gAl = (const char*)Al + (size_t)rt * 16384;
    const char* gBh = (const char*)T2h + (size_t)q * 32768 + (size_t)rh * 16384;
    const char* gBl = (const char*)T2l + (size_t)q * 32768 + (size_t)rh * 16384;
#pragma unroll
    for (int ch = 0; ch < 4; ++ch) {
        const int off = ch * 4096 + t * 16;
        gld_lds16(gAh + off, (char*)sAh + off);
        gld_lds16(gAl + off, (char*)sAl + off);
        gld_lds16(gBh + off, (char*)sBh + off);
        gld_lds16(gBl + off, (char*)sBl + off);
    }
    __syncthreads();

    const int lane = t & 63;
    const int wid  = t >> 6;
    const int pb   = (wid >> 1) * 64;   // wave row base within 128
    const int rb   = (wid & 1) * 64;    // wave col base within 128
    const int lr   = lane & 15;         // fragment row/col lane index
    const int lk   = (lane >> 4) * 16;  // k-group byte offset (8 bf16)

    f32x4 acc[4][4] = {};

    const unsigned short* pA[3] = {sAh, sAh, sAl};
    const unsigned short* pB[3] = {sBh, sBl, sBh};
#pragma unroll
    for (int pass = 0; pass < 3; ++pass) {
        const unsigned short* Am = pA[pass];
        const unsigned short* Bm = pB[pass];
#pragma unroll
        for (int kc = 0; kc < 2; ++kc) {
            const int kb = kc * 64 + lk;  // byte offset of this lane's k chunk
            bf16x8 af[4], bfr[4];
#pragma unroll
            for (int fm = 0; fm < 4; ++fm) {
                const int row = pb + fm * 16 + lr;
                af[fm] = *(const bf16x8*)((const char*)Am + row * 128 + (kb ^ ((row & 7) << 4)));
            }
#pragma unroll
            for (int fn = 0; fn < 4; ++fn) {
                const int row = rb + fn * 16 + lr;
                bfr[fn] = *(const bf16x8*)((const char*)Bm + row * 128 + (kb ^ ((row & 7) << 4)));
            }
#pragma unroll
            for (int fm = 0; fm < 4; ++fm)
#pragma unroll
                for (int fn = 0; fn < 4; ++fn)
                    acc[fm][fn] = __builtin_amdgcn_mfma_f32_16x16x32_bf16(
                        af[fm], bfr[fn], acc[fm][fn], 0, 0, 0);
        }
    }

    // C/D layout (m89-verified): col = lane&15, row = (lane>>4)*4 + reg
    const size_t colbase = (size_t)q * 256 + (size_t)rh * 128 + rb + lr;
    const int rowbase = rt * 128 + pb + (lane >> 4) * 4;
#pragma unroll
    for (int fm = 0; fm < 4; ++fm) {
#pragma unroll
        for (int j = 0; j < 4; ++j) {
            float* orow = out + (size_t)(rowbase + fm * 16 + j) * 65536 + colbase;
#pragma unroll
            for (int fn = 0; fn < 4; ++fn) orow[fn * 16] = acc[fm][fn][j];
        }
    }
}

extern "C" void kernel_launch(void* const* d_in, const int* in_sizes, int n_in,
                              void* d_out, int out_size, void* d_ws, size_t ws_size,
                              hipStream_t stream) {
    const float* c = (const float*)d_in[0];
    const float* b = (const float*)d_in[1];
    const float* a = (const float*)d_in[2];
    const float* W = (const float*)d_in[3];
    float* out = (float*)d_out;

    // workspace: bs[16384 f32] | T1[1048576 f32] | Ah[131072 bf16] | Al | T2h[4194304 bf16] | T2l
    // = 64K + 4M + 256K + 256K + 8M + 8M bytes ~= 20.6 MiB
    float* bs = (float*)d_ws;
    float* T1 = bs + 16384;
    unsigned short* Ah = (unsigned short*)(T1 + 1048576);
    unsigned short* Al = Ah + 131072;
    unsigned short* T2h = Al + 131072;
    unsigned short* T2l = T2h + 4194304;

    hipLaunchKernelGGL(bsum_kernel, dim3(64), dim3(256), 0, stream, b, bs);
    hipLaunchKernelGGL(aprep_kernel, dim3(128), dim3(256), 0, stream, a, Ah, Al);
    hipLaunchKernelGGL(step1_kernel, dim3(64, 4), dim3(256), 0, stream, c, W, T1);
    hipLaunchKernelGGL(step2_kernel, dim3(256, 4), dim3(256), 0, stream, bs, T1, T2h, T2l);
    hipLaunchKernelGGL(step3_kernel, dim3(32, 256), dim3(256), 0, stream, Ah, Al, T2h, T2l, out);
}